// Round 2
// baseline (1722.601 us; speedup 1.0000x reference)
//
#include <hip/hip_runtime.h>
#include <math.h>

// AtnConv (contextual attention) B=2, H=W=64, C=128, k=3.
// Pipeline per batch: D = X2·X2^T ; invn from diag-stencil of diag(D);
// G = 9-tap diagonal stencil of D (diagonal-run reuse T=8);
// P = pooled/scaled logits + per-row softmax stats (vertical-run reuse T=8);
// Y = A2 @ X1 with A2 generated on the fly from P inside the GEMM (fused).
// ws: buf1 (D then P) 64MB, buf2 (G) 64MB, invn/rowm/rowrz 48KB.

constexpr int Hh = 64;
constexpr int Ww = 64;
constexpr int CDIM = 128;
constexpr int LDIM = Hh * Ww;   // 4096

// ---------------------------------------------------------------- GEMM: D = X Xt
__global__ __launch_bounds__(256)
void k_gemm_d(const float* __restrict__ X, float* __restrict__ D) {
    constexpr int BM = 128, BN = 128, BK = 16;
    __shared__ float As[BK][BM + 4];
    __shared__ float Bs[BK][BN + 4];
    const int t  = threadIdx.x;
    const int bm = blockIdx.x * BM;
    const int bn = blockIdx.y * BN;
    const int tm = (t >> 4) << 3;
    const int tn = (t & 15) << 3;
    const int lr = t >> 1;
    const int lc = (t & 1) << 3;
    float acc[8][8] = {};
    for (int k0 = 0; k0 < CDIM; k0 += BK) {
        const float4 a0 = *(const float4*)(X + (size_t)(bm + lr) * CDIM + k0 + lc);
        const float4 a1 = *(const float4*)(X + (size_t)(bm + lr) * CDIM + k0 + lc + 4);
        const float4 b0 = *(const float4*)(X + (size_t)(bn + lr) * CDIM + k0 + lc);
        const float4 b1 = *(const float4*)(X + (size_t)(bn + lr) * CDIM + k0 + lc + 4);
        As[lc + 0][lr] = a0.x; As[lc + 1][lr] = a0.y; As[lc + 2][lr] = a0.z; As[lc + 3][lr] = a0.w;
        As[lc + 4][lr] = a1.x; As[lc + 5][lr] = a1.y; As[lc + 6][lr] = a1.z; As[lc + 7][lr] = a1.w;
        Bs[lc + 0][lr] = b0.x; Bs[lc + 1][lr] = b0.y; Bs[lc + 2][lr] = b0.z; Bs[lc + 3][lr] = b0.w;
        Bs[lc + 4][lr] = b1.x; Bs[lc + 5][lr] = b1.y; Bs[lc + 6][lr] = b1.z; Bs[lc + 7][lr] = b1.w;
        __syncthreads();
        #pragma unroll
        for (int k = 0; k < BK; ++k) {
            float a[8], b[8];
            *(float4*)(a)     = *(const float4*)(&As[k][tm]);
            *(float4*)(a + 4) = *(const float4*)(&As[k][tm + 4]);
            *(float4*)(b)     = *(const float4*)(&Bs[k][tn]);
            *(float4*)(b + 4) = *(const float4*)(&Bs[k][tn + 4]);
            #pragma unroll
            for (int i = 0; i < 8; ++i)
                #pragma unroll
                for (int j = 0; j < 8; ++j)
                    acc[i][j] = fmaf(a[i], b[j], acc[i][j]);
        }
        __syncthreads();
    }
    #pragma unroll
    for (int i = 0; i < 8; ++i) {
        float4 w0 = make_float4(acc[i][0], acc[i][1], acc[i][2], acc[i][3]);
        float4 w1 = make_float4(acc[i][4], acc[i][5], acc[i][6], acc[i][7]);
        *(float4*)(D + (size_t)(bm + tm + i) * LDIM + bn + tn)     = w0;
        *(float4*)(D + (size_t)(bm + tm + i) * LDIM + bn + tn + 4) = w1;
    }
}

// ------------------------------------------------- invn[l] = 1/max(sqrt(.),eps)
__global__ void k_invnorm(const float* __restrict__ D, float* __restrict__ invn) {
    const int l = blockIdx.x * 256 + threadIdx.x;
    const int ly = l >> 6, lx = l & 63;
    float s = 0.f;
    #pragma unroll
    for (int ty = -1; ty <= 1; ++ty)
        #pragma unroll
        for (int tx = -1; tx <= 1; ++tx) {
            if ((unsigned)(ly + ty) < 64u && (unsigned)(lx + tx) < 64u) {
                const int q = l + ty * Ww + tx;
                s += D[(size_t)q * LDIM + q];
            }
        }
    invn[l] = 1.0f / fmaxf(sqrtf(s), 1e-4f);
}

// ---------------- G[x,l] = sum_t D[x+t,l+t], diagonal-run reuse (T=8 outputs/thread)
__global__ __launch_bounds__(256)
void k_gdiag(const float* __restrict__ D, float* __restrict__ G) {
    constexpr int T = 8;
    const int l0 = blockIdx.x * 256 + threadIdx.x;
    const int x0 = blockIdx.y * T;
    const int xyc = x0 >> 6;        // constant within band (x0 multiple of 8)
    const int xxb = x0 & 63;        // xx = xxb + i, stays < 64
    if (l0 <= LDIM - T) {
        float acc[T] = {};
        #pragma unroll
        for (int c = 0; c < 3; ++c) {
            const int bc = c * 64 - 65;          // -65, -1, 63
            const int ty = c - 1;
            const bool vyx = (unsigned)(xyc + ty) < 64u;
            float w[T + 2];
            #pragma unroll
            for (int u = 0; u < T + 2; ++u) {
                const int r  = x0 + bc + u;
                const int cc = l0 + bc + u;
                w[u] = ((unsigned)r < (unsigned)LDIM && (unsigned)cc < (unsigned)LDIM)
                         ? D[(size_t)r * LDIM + cc] : 0.f;
            }
            if (vyx) {
                #pragma unroll
                for (int i = 0; i < T; ++i) {
                    const int l = l0 + i;
                    const int ly = l >> 6, lx = l & 63;
                    if ((unsigned)(ly + ty) < 64u) {
                        const int xx = xxb + i;
                        if (xx > 0 && lx > 0)   acc[i] += w[i];
                        acc[i] += w[i + 1];
                        if (xx < 63 && lx < 63) acc[i] += w[i + 2];
                    }
                }
            }
        }
        #pragma unroll
        for (int i = 0; i < T; ++i)
            G[(size_t)(x0 + i) * LDIM + (l0 + i)] = acc[i];
    } else {
        // wrap slow path (only threads with l0 > 4088)
        for (int i = 0; i < T; ++i) {
            const int l = (l0 + i) & (LDIM - 1);
            const int ly = l >> 6, lx = l & 63;
            const int x = x0 + i;
            const int xy = x >> 6, xx = x & 63;
            float s = 0.f;
            #pragma unroll
            for (int ty = -1; ty <= 1; ++ty)
                #pragma unroll
                for (int tx = -1; tx <= 1; ++tx) {
                    if ((unsigned)(xy + ty) < 64u && (unsigned)(xx + tx) < 64u &&
                        (unsigned)(ly + ty) < 64u && (unsigned)(lx + tx) < 64u) {
                        const int off = ty * Ww + tx;
                        s += D[(size_t)(x + off) * LDIM + (l + off)];
                    }
                }
            G[(size_t)x * LDIM + l] = s;
        }
    }
}

// ------- P[x,l] = (90/cnt)*invn[l]*sum_s G[x+s,l]; vertical-run reuse + row stats
__global__ __launch_bounds__(256)
void k_pool_stats(const float* __restrict__ G, const float* __restrict__ invn,
                  float* __restrict__ Pout, float* __restrict__ rowm,
                  float* __restrict__ rowrz) {
    constexpr int T = 8;
    const int x0 = blockIdx.x * T;
    const int t  = threadIdx.x;
    const int xyc = x0 >> 6;
    const int xxb = x0 & 63;
    const int cy = 1 + (xyc > 0) + (xyc < 63);
    float sc[T];
    #pragma unroll
    for (int i = 0; i < T; ++i) {
        const int xx = xxb + i;
        sc[i] = 90.0f / (float)(cy * (1 + (xx > 0) + (xx < 63)));
    }
    float m[T], Z[T];
    #pragma unroll
    for (int i = 0; i < T; ++i) { m[i] = -1e30f; Z[i] = 0.f; }

    for (int ch = 0; ch < LDIM / 256; ++ch) {
        const int l = ch * 256 + t;
        const float inl = invn[l];
        float acc[T] = {};
        #pragma unroll
        for (int c = 0; c < 3; ++c) {
            const int bc = c * 64 - 65;
            const int ty = c - 1;
            float w[T + 2];
            #pragma unroll
            for (int u = 0; u < T + 2; ++u) {
                const int r = x0 + bc + u;
                w[u] = ((unsigned)r < (unsigned)LDIM) ? G[(size_t)r * LDIM + l] : 0.f;
            }
            if ((unsigned)(xyc + ty) < 64u) {
                #pragma unroll
                for (int i = 0; i < T; ++i) {
                    const int xx = xxb + i;
                    if (xx > 0)  acc[i] += w[i];
                    acc[i] += w[i + 1];
                    if (xx < 63) acc[i] += w[i + 2];
                }
            }
        }
        #pragma unroll
        for (int i = 0; i < T; ++i) {
            const float p = acc[i] * sc[i] * inl;
            Pout[(size_t)(x0 + i) * LDIM + l] = p;
            const float nm = fmaxf(m[i], p);
            Z[i] = Z[i] * __expf(m[i] - nm) + __expf(p - nm);
            m[i] = nm;
        }
    }
    __shared__ float sm[256], sz[256];
    for (int i = 0; i < T; ++i) {
        __syncthreads();
        sm[t] = m[i]; sz[t] = Z[i];
        __syncthreads();
        for (int off = 128; off > 0; off >>= 1) {
            if (t < off) {
                const float m2 = sm[t + off], z2 = sz[t + off];
                const float nm = fmaxf(sm[t], m2);
                sz[t] = sz[t] * __expf(sm[t] - nm) + z2 * __expf(m2 - nm);
                sm[t] = nm;
            }
            __syncthreads();
        }
        if (t == 0) { rowm[x0 + i] = sm[0]; rowrz[x0 + i] = 1.0f / sz[0]; }
    }
}

// ---------- Y += A2 @ X1, A2 tile generated on the fly from P (fused att2+gemm)
__global__ __launch_bounds__(256)
void k_gemm_y(const float* __restrict__ P, const float* __restrict__ rowm,
              const float* __restrict__ rowrz, const float* __restrict__ X1v,
              float* __restrict__ Y) {
    constexpr int BM = 64, BK = 32, KS = 512;
    __shared__ float As[BK][BM + 4];       // A2 tile [k][p]
    __shared__ float Bs[BK][CDIM + 4];
    __shared__ float s_m[BM + 130];        // rowm for u in [bm-65, bm+129)
    __shared__ float s_rz[BM + 130];
    const int t  = threadIdx.x;
    const int bm = blockIdx.x * BM;
    const int ks = blockIdx.y * KS;
    for (int j = t; j < BM + 130; j += 256) {
        const int u = bm - 65 + j;
        const bool ok = (unsigned)u < (unsigned)LDIM;
        s_m[j]  = ok ? rowm[u]  : 0.f;
        s_rz[j] = ok ? rowrz[u] : 0.f;
    }
    const int tm  = (t >> 5) << 3;
    const int tn  = (t & 31) << 2;
    const int kq  = t & 31;       // generation: col within k-tile
    const int pe0 = t >> 5;       // generation: p_l = e*8 + pe0
    float acc[8][4] = {};
    __syncthreads();
    for (int kk = 0; kk < KS; kk += BK) {
        const int k0 = ks + kk;
        // ---- generate A2 tile from P
        const int q  = k0 + kq;
        const int qy = q >> 6, qx = q & 63;
        #pragma unroll
        for (int e = 0; e < 8; ++e) {
            const int p_l = e * 8 + pe0;
            const int p   = bm + p_l;
            const int py  = p >> 6, px = p & 63;
            float a = 0.f;
            #pragma unroll
            for (int ty = -1; ty <= 1; ++ty)
                #pragma unroll
                for (int tx = -1; tx <= 1; ++tx) {
                    if ((unsigned)(py + ty) < 64u && (unsigned)(px + tx) < 64u &&
                        (unsigned)(qy + ty) < 64u && (unsigned)(qx + tx) < 64u) {
                        const int off = ty * Ww + tx;
                        const int u   = p + off;
                        const int j   = p_l + off + 65;
                        a += __expf(P[(size_t)u * LDIM + (q + off)] - s_m[j]) * s_rz[j];
                    }
                }
            As[kq][p_l] = a;
        }
        // ---- B tile
        {
            const int r  = t >> 3;
            const int cb = (t & 7) << 4;
            const float* src = X1v + (size_t)(k0 + r) * CDIM + cb;
            *(float4*)(&Bs[r][cb])      = *(const float4*)(src);
            *(float4*)(&Bs[r][cb + 4])  = *(const float4*)(src + 4);
            *(float4*)(&Bs[r][cb + 8])  = *(const float4*)(src + 8);
            *(float4*)(&Bs[r][cb + 12]) = *(const float4*)(src + 12);
        }
        __syncthreads();
        #pragma unroll
        for (int k = 0; k < BK; ++k) {
            float av[8], bv[4];
            *(float4*)(av)     = *(const float4*)(&As[k][tm]);
            *(float4*)(av + 4) = *(const float4*)(&As[k][tm + 4]);
            *(float4*)(bv)     = *(const float4*)(&Bs[k][tn]);
            #pragma unroll
            for (int i = 0; i < 8; ++i)
                #pragma unroll
                for (int j = 0; j < 4; ++j)
                    acc[i][j] = fmaf(av[i], bv[j], acc[i][j]);
        }
        __syncthreads();
    }
    #pragma unroll
    for (int i = 0; i < 8; ++i)
        #pragma unroll
        for (int j = 0; j < 4; ++j)
            atomicAdd(Y + (size_t)(bm + tm + i) * CDIM + tn + j, acc[i][j]);
}

extern "C" void kernel_launch(void* const* d_in, const int* in_sizes, int n_in,
                              void* d_out, int out_size, void* d_ws, size_t ws_size,
                              hipStream_t stream) {
    const float* x1 = (const float*)d_in[0];
    const float* x2 = (const float*)d_in[1];
    float* out = (float*)d_out;

    const size_t MATB = (size_t)LDIM * LDIM * sizeof(float);
    char* ws = (char*)d_ws;
    float* buf1  = (float*)ws;                   // D, then P
    float* buf2  = (float*)(ws + MATB);          // G
    float* invn  = (float*)(ws + 2 * MATB);
    float* rowm  = invn + LDIM;
    float* rowrz = rowm + LDIM;

    const int B = in_sizes[0] / (LDIM * CDIM);

    hipMemsetAsync(d_out, 0, (size_t)out_size * sizeof(float), stream);

    for (int b = 0; b < B; ++b) {
        const float* X2b = x2 + (size_t)b * LDIM * CDIM;
        const float* X1b = x1 + (size_t)b * LDIM * CDIM;
        float* Yb = out + (size_t)b * LDIM * CDIM;

        k_gemm_d    <<<dim3(LDIM / 128, LDIM / 128), 256, 0, stream>>>(X2b, buf1);
        k_invnorm   <<<LDIM / 256, 256, 0, stream>>>(buf1, invn);
        k_gdiag     <<<dim3(LDIM / 256, LDIM / 8), 256, 0, stream>>>(buf1, buf2);
        k_pool_stats<<<LDIM / 8, 256, 0, stream>>>(buf2, invn, buf1, rowm, rowrz);
        k_gemm_y    <<<dim3(LDIM / 64, 8), 256, 0, stream>>>(buf1, rowm, rowrz, X1b, Yb);
    }
}

// Round 3
// 750.066 us; speedup vs baseline: 2.2966x; 2.2966x over previous
//
#include <hip/hip_runtime.h>
#include <math.h>

// AtnConv (contextual attention) B=2, H=W=64, C=128, k=3.
// Per batch: D = X2·X2^T ; invn from diag(D) stencil; G = 9-tap diagonal
// stencil of D (T=8 run reuse); P = pooled logits + row softmax stats
// (T=8 vertical reuse); A2 = 9-tap diagonal stencil of softmax(P)
// (T=8 diagonal reuse, shared exp); Y = A2 @ X1 (split-K fp32 GEMM).
// ws: buf1 (D then P) 64MB, buf2 (G then A2) 64MB, invn/rowm/rowrz 48KB.

constexpr int Hh = 64;
constexpr int Ww = 64;
constexpr int CDIM = 128;
constexpr int LDIM = Hh * Ww;   // 4096

// ---------------------------------------------------------------- GEMM: D = X Xt
__global__ __launch_bounds__(256)
void k_gemm_d(const float* __restrict__ X, float* __restrict__ D) {
    constexpr int BM = 128, BN = 128, BK = 16;
    __shared__ float As[BK][BM + 4];
    __shared__ float Bs[BK][BN + 4];
    const int t  = threadIdx.x;
    const int bm = blockIdx.x * BM;
    const int bn = blockIdx.y * BN;
    const int tm = (t >> 4) << 3;
    const int tn = (t & 15) << 3;
    const int lr = t >> 1;
    const int lc = (t & 1) << 3;
    float acc[8][8] = {};
    for (int k0 = 0; k0 < CDIM; k0 += BK) {
        const float4 a0 = *(const float4*)(X + (size_t)(bm + lr) * CDIM + k0 + lc);
        const float4 a1 = *(const float4*)(X + (size_t)(bm + lr) * CDIM + k0 + lc + 4);
        const float4 b0 = *(const float4*)(X + (size_t)(bn + lr) * CDIM + k0 + lc);
        const float4 b1 = *(const float4*)(X + (size_t)(bn + lr) * CDIM + k0 + lc + 4);
        As[lc + 0][lr] = a0.x; As[lc + 1][lr] = a0.y; As[lc + 2][lr] = a0.z; As[lc + 3][lr] = a0.w;
        As[lc + 4][lr] = a1.x; As[lc + 5][lr] = a1.y; As[lc + 6][lr] = a1.z; As[lc + 7][lr] = a1.w;
        Bs[lc + 0][lr] = b0.x; Bs[lc + 1][lr] = b0.y; Bs[lc + 2][lr] = b0.z; Bs[lc + 3][lr] = b0.w;
        Bs[lc + 4][lr] = b1.x; Bs[lc + 5][lr] = b1.y; Bs[lc + 6][lr] = b1.z; Bs[lc + 7][lr] = b1.w;
        __syncthreads();
        #pragma unroll
        for (int k = 0; k < BK; ++k) {
            float a[8], b[8];
            *(float4*)(a)     = *(const float4*)(&As[k][tm]);
            *(float4*)(a + 4) = *(const float4*)(&As[k][tm + 4]);
            *(float4*)(b)     = *(const float4*)(&Bs[k][tn]);
            *(float4*)(b + 4) = *(const float4*)(&Bs[k][tn + 4]);
            #pragma unroll
            for (int i = 0; i < 8; ++i)
                #pragma unroll
                for (int j = 0; j < 8; ++j)
                    acc[i][j] = fmaf(a[i], b[j], acc[i][j]);
        }
        __syncthreads();
    }
    #pragma unroll
    for (int i = 0; i < 8; ++i) {
        float4 w0 = make_float4(acc[i][0], acc[i][1], acc[i][2], acc[i][3]);
        float4 w1 = make_float4(acc[i][4], acc[i][5], acc[i][6], acc[i][7]);
        *(float4*)(D + (size_t)(bm + tm + i) * LDIM + bn + tn)     = w0;
        *(float4*)(D + (size_t)(bm + tm + i) * LDIM + bn + tn + 4) = w1;
    }
}

// ------------------------------------------------- invn[l] = 1/max(sqrt(.),eps)
__global__ void k_invnorm(const float* __restrict__ D, float* __restrict__ invn) {
    const int l = blockIdx.x * 256 + threadIdx.x;
    const int ly = l >> 6, lx = l & 63;
    float s = 0.f;
    #pragma unroll
    for (int ty = -1; ty <= 1; ++ty)
        #pragma unroll
        for (int tx = -1; tx <= 1; ++tx) {
            if ((unsigned)(ly + ty) < 64u && (unsigned)(lx + tx) < 64u) {
                const int q = l + ty * Ww + tx;
                s += D[(size_t)q * LDIM + q];
            }
        }
    invn[l] = 1.0f / fmaxf(sqrtf(s), 1e-4f);
}

// ---------------- G[x,l] = sum_t D[x+t,l+t], diagonal-run reuse (T=8 outputs/thread)
__global__ __launch_bounds__(256)
void k_gdiag(const float* __restrict__ D, float* __restrict__ G) {
    constexpr int T = 8;
    const int l0 = blockIdx.x * 256 + threadIdx.x;
    const int x0 = blockIdx.y * T;
    const int xyc = x0 >> 6;
    const int xxb = x0 & 63;
    if (l0 <= LDIM - T) {
        float acc[T] = {};
        #pragma unroll
        for (int c = 0; c < 3; ++c) {
            const int bc = c * 64 - 65;          // -65, -1, 63
            const int ty = c - 1;
            const bool vyx = (unsigned)(xyc + ty) < 64u;
            float w[T + 2];
            #pragma unroll
            for (int u = 0; u < T + 2; ++u) {
                const int r  = x0 + bc + u;
                const int cc = l0 + bc + u;
                w[u] = ((unsigned)r < (unsigned)LDIM && (unsigned)cc < (unsigned)LDIM)
                         ? D[(size_t)r * LDIM + cc] : 0.f;
            }
            if (vyx) {
                #pragma unroll
                for (int i = 0; i < T; ++i) {
                    const int l = l0 + i;
                    const int ly = l >> 6, lx = l & 63;
                    if ((unsigned)(ly + ty) < 64u) {
                        const int xx = xxb + i;
                        if (xx > 0 && lx > 0)   acc[i] += w[i];
                        acc[i] += w[i + 1];
                        if (xx < 63 && lx < 63) acc[i] += w[i + 2];
                    }
                }
            }
        }
        #pragma unroll
        for (int i = 0; i < T; ++i)
            G[(size_t)(x0 + i) * LDIM + (l0 + i)] = acc[i];
    } else {
        for (int i = 0; i < T; ++i) {
            const int l = (l0 + i) & (LDIM - 1);
            const int ly = l >> 6, lx = l & 63;
            const int x = x0 + i;
            const int xy = x >> 6, xx = x & 63;
            float s = 0.f;
            #pragma unroll
            for (int ty = -1; ty <= 1; ++ty)
                #pragma unroll
                for (int tx = -1; tx <= 1; ++tx) {
                    if ((unsigned)(xy + ty) < 64u && (unsigned)(xx + tx) < 64u &&
                        (unsigned)(ly + ty) < 64u && (unsigned)(lx + tx) < 64u) {
                        const int off = ty * Ww + tx;
                        s += D[(size_t)(x + off) * LDIM + (l + off)];
                    }
                }
            G[(size_t)x * LDIM + l] = s;
        }
    }
}

// ------- P[x,l] = (90/cnt)*invn[l]*sum_s G[x+s,l]; vertical-run reuse + row stats
__global__ __launch_bounds__(256)
void k_pool_stats(const float* __restrict__ G, const float* __restrict__ invn,
                  float* __restrict__ Pout, float* __restrict__ rowm,
                  float* __restrict__ rowrz) {
    constexpr int T = 8;
    const int x0 = blockIdx.x * T;
    const int t  = threadIdx.x;
    const int xyc = x0 >> 6;
    const int xxb = x0 & 63;
    const int cy = 1 + (xyc > 0) + (xyc < 63);
    float sc[T];
    #pragma unroll
    for (int i = 0; i < T; ++i) {
        const int xx = xxb + i;
        sc[i] = 90.0f / (float)(cy * (1 + (xx > 0) + (xx < 63)));
    }
    float m[T], Z[T];
    #pragma unroll
    for (int i = 0; i < T; ++i) { m[i] = -1e30f; Z[i] = 0.f; }

    for (int ch = 0; ch < LDIM / 256; ++ch) {
        const int l = ch * 256 + t;
        const float inl = invn[l];
        float acc[T] = {};
        #pragma unroll
        for (int c = 0; c < 3; ++c) {
            const int bc = c * 64 - 65;
            const int ty = c - 1;
            float w[T + 2];
            #pragma unroll
            for (int u = 0; u < T + 2; ++u) {
                const int r = x0 + bc + u;
                w[u] = ((unsigned)r < (unsigned)LDIM) ? G[(size_t)r * LDIM + l] : 0.f;
            }
            if ((unsigned)(xyc + ty) < 64u) {
                #pragma unroll
                for (int i = 0; i < T; ++i) {
                    const int xx = xxb + i;
                    if (xx > 0)  acc[i] += w[i];
                    acc[i] += w[i + 1];
                    if (xx < 63) acc[i] += w[i + 2];
                }
            }
        }
        #pragma unroll
        for (int i = 0; i < T; ++i) {
            const float p = acc[i] * sc[i] * inl;
            Pout[(size_t)(x0 + i) * LDIM + l] = p;
            const float nm = fmaxf(m[i], p);
            Z[i] = Z[i] * __expf(m[i] - nm) + __expf(p - nm);
            m[i] = nm;
        }
    }
    __shared__ float sm[256], sz[256];
    for (int i = 0; i < T; ++i) {
        __syncthreads();
        sm[t] = m[i]; sz[t] = Z[i];
        __syncthreads();
        for (int off = 128; off > 0; off >>= 1) {
            if (t < off) {
                const float m2 = sm[t + off], z2 = sz[t + off];
                const float nm = fmaxf(sm[t], m2);
                sz[t] = sz[t] * __expf(sm[t] - nm) + z2 * __expf(m2 - nm);
                sm[t] = nm;
            }
            __syncthreads();
        }
        if (t == 0) { rowm[x0 + i] = sm[0]; rowrz[x0 + i] = 1.0f / sz[0]; }
    }
}

// ---- A2[p,q] = sum_t exp(P[p+t,q+t]-m_{p+t})*rz_{p+t}; T=8 diagonal reuse,
//      shared per-tap exp across the outputs that consume it.
__global__ __launch_bounds__(256)
void k_att2(const float* __restrict__ P, const float* __restrict__ rowm,
            const float* __restrict__ rowrz, float* __restrict__ A2) {
    constexpr int T = 8;
    const int q0 = blockIdx.x * 256 + threadIdx.x;
    const int p0 = blockIdx.y * T;
    const int pyc = p0 >> 6;
    const int pxb = p0 & 63;
    if (q0 <= LDIM - T) {
        float acc[T] = {};
        #pragma unroll
        for (int c = 0; c < 3; ++c) {
            const int bc = c * 64 - 65;          // -65, -1, 63
            const int ty = c - 1;
            if ((unsigned)(pyc + ty) < 64u) {
                float e[T + 2];
                #pragma unroll
                for (int u = 0; u < T + 2; ++u) {
                    const int r  = p0 + bc + u;
                    const int cc = q0 + bc + u;
                    if ((unsigned)r < (unsigned)LDIM && (unsigned)cc < (unsigned)LDIM)
                        e[u] = __expf(P[(size_t)r * LDIM + cc] - rowm[r]) * rowrz[r];
                    else
                        e[u] = 0.f;
                }
                #pragma unroll
                for (int i = 0; i < T; ++i) {
                    const int q = q0 + i;
                    const int qy = q >> 6, qx = q & 63;
                    if ((unsigned)(qy + ty) < 64u) {
                        const int px = pxb + i;
                        if (px > 0 && qx > 0)   acc[i] += e[i];
                        acc[i] += e[i + 1];
                        if (px < 63 && qx < 63) acc[i] += e[i + 2];
                    }
                }
            }
        }
        #pragma unroll
        for (int i = 0; i < T; ++i)
            A2[(size_t)(p0 + i) * LDIM + (q0 + i)] = acc[i];
    } else {
        for (int i = 0; i < T; ++i) {
            const int q = (q0 + i) & (LDIM - 1);
            const int qy = q >> 6, qx = q & 63;
            const int p = p0 + i;
            const int py = p >> 6, px = p & 63;
            float s = 0.f;
            #pragma unroll
            for (int ty = -1; ty <= 1; ++ty)
                #pragma unroll
                for (int tx = -1; tx <= 1; ++tx) {
                    if ((unsigned)(py + ty) < 64u && (unsigned)(px + tx) < 64u &&
                        (unsigned)(qy + ty) < 64u && (unsigned)(qx + tx) < 64u) {
                        const int off = ty * Ww + tx;
                        const int u = p + off;
                        s += __expf(P[(size_t)u * LDIM + (q + off)] - rowm[u]) * rowrz[u];
                    }
                }
            A2[(size_t)p * LDIM + q] = s;
        }
    }
}

// ---------------------------------------------- Y += A2 @ X1  (split-K, atomic f32)
__global__ __launch_bounds__(256)
void k_gemm_y(const float* __restrict__ A2, const float* __restrict__ X1v,
              float* __restrict__ Y) {
    constexpr int BM = 64, BK = 32, KS = 512;
    __shared__ float As[BK][BM + 4];
    __shared__ float Bs[BK][CDIM + 4];
    const int t = threadIdx.x;
    const int bm = blockIdx.x * BM;
    const int kbase = blockIdx.y * KS;
    const int tm = (t >> 5) << 3;
    const int tn = (t & 31) << 2;
    const int ar = t >> 2, ac = (t & 3) << 3;
    const int br = t >> 3, bc = (t & 7) << 4;
    float acc[8][4] = {};
    for (int ks = 0; ks < KS; ks += BK) {
        const int k0 = kbase + ks;
        const float4 a0 = *(const float4*)(A2 + (size_t)(bm + ar) * LDIM + k0 + ac);
        const float4 a1 = *(const float4*)(A2 + (size_t)(bm + ar) * LDIM + k0 + ac + 4);
        As[ac + 0][ar] = a0.x; As[ac + 1][ar] = a0.y; As[ac + 2][ar] = a0.z; As[ac + 3][ar] = a0.w;
        As[ac + 4][ar] = a1.x; As[ac + 5][ar] = a1.y; As[ac + 6][ar] = a1.z; As[ac + 7][ar] = a1.w;
        const float* src = X1v + (size_t)(k0 + br) * CDIM + bc;
        *(float4*)(&Bs[br][bc])      = *(const float4*)(src);
        *(float4*)(&Bs[br][bc + 4])  = *(const float4*)(src + 4);
        *(float4*)(&Bs[br][bc + 8])  = *(const float4*)(src + 8);
        *(float4*)(&Bs[br][bc + 12]) = *(const float4*)(src + 12);
        __syncthreads();
        #pragma unroll
        for (int k = 0; k < BK; ++k) {
            float a[8], b[4];
            *(float4*)(a)     = *(const float4*)(&As[k][tm]);
            *(float4*)(a + 4) = *(const float4*)(&As[k][tm + 4]);
            *(float4*)(b)     = *(const float4*)(&Bs[k][tn]);
            #pragma unroll
            for (int i = 0; i < 8; ++i)
                #pragma unroll
                for (int j = 0; j < 4; ++j)
                    acc[i][j] = fmaf(a[i], b[j], acc[i][j]);
        }
        __syncthreads();
    }
    #pragma unroll
    for (int i = 0; i < 8; ++i)
        #pragma unroll
        for (int j = 0; j < 4; ++j)
            atomicAdd(Y + (size_t)(bm + tm + i) * CDIM + tn + j, acc[i][j]);
}

extern "C" void kernel_launch(void* const* d_in, const int* in_sizes, int n_in,
                              void* d_out, int out_size, void* d_ws, size_t ws_size,
                              hipStream_t stream) {
    const float* x1 = (const float*)d_in[0];
    const float* x2 = (const float*)d_in[1];
    float* out = (float*)d_out;

    const size_t MATB = (size_t)LDIM * LDIM * sizeof(float);
    char* ws = (char*)d_ws;
    float* buf1  = (float*)ws;                   // D, then P
    float* buf2  = (float*)(ws + MATB);          // G, then A2
    float* invn  = (float*)(ws + 2 * MATB);
    float* rowm  = invn + LDIM;
    float* rowrz = rowm + LDIM;

    const int B = in_sizes[0] / (LDIM * CDIM);

    hipMemsetAsync(d_out, 0, (size_t)out_size * sizeof(float), stream);

    for (int b = 0; b < B; ++b) {
        const float* X2b = x2 + (size_t)b * LDIM * CDIM;
        const float* X1b = x1 + (size_t)b * LDIM * CDIM;
        float* Yb = out + (size_t)b * LDIM * CDIM;

        k_gemm_d    <<<dim3(LDIM / 128, LDIM / 128), 256, 0, stream>>>(X2b, buf1);
        k_invnorm   <<<LDIM / 256, 256, 0, stream>>>(buf1, invn);
        k_gdiag     <<<dim3(LDIM / 256, LDIM / 8), 256, 0, stream>>>(buf1, buf2);
        k_pool_stats<<<LDIM / 8, 256, 0, stream>>>(buf2, invn, buf1, rowm, rowrz);
        k_att2      <<<dim3(LDIM / 256, LDIM / 8), 256, 0, stream>>>(buf1, rowm, rowrz, buf2);
        k_gemm_y    <<<dim3(LDIM / 64, 8), 256, 0, stream>>>(buf2, X1b, Yb);
    }
}

// Round 4
// 615.540 us; speedup vs baseline: 2.7985x; 1.2185x over previous
//
#include <hip/hip_runtime.h>
#include <hip/hip_bf16.h>
#include <math.h>

// AtnConv (contextual attention) B=2, H=W=64, C=128, k=3.
// Score path fp32: D = X2·X2^T (split-bf16 MFMA: Xh·Xh^T + Xh·Xl^T + Xl·Xh^T);
// invn; G = 9-tap diag stencil of D; P = pooled logits + row softmax stats.
// Value path bf16: A2 = diag stencil of softmax(P) stored bf16;
// Y = A2 @ X1 via bf16 MFMA (split-K=8, atomic f32).
// ws: buf1 (D->P) 64MB; buf2 (X2h/X2l -> G -> A2bf|X1T) 64MB; invn/rowm/rowrz.

constexpr int Hh = 64;
constexpr int Ww = 64;
constexpr int CDIM = 128;
constexpr int LDIM = Hh * Ww;   // 4096

typedef __attribute__((ext_vector_type(8))) short bf16x8;
typedef __attribute__((ext_vector_type(4))) float f32x4;

// --------------------------------------------- split X2 into bf16 hi/lo parts
__global__ __launch_bounds__(256)
void k_split(const float* __restrict__ X, __hip_bfloat16* __restrict__ Xh,
             __hip_bfloat16* __restrict__ Xl) {
    const int i = (blockIdx.x * 256 + threadIdx.x) * 4;
    const float4 v = *(const float4*)(X + i);
    __hip_bfloat16 h[4], l[4];
    const float f[4] = {v.x, v.y, v.z, v.w};
    #pragma unroll
    for (int j = 0; j < 4; ++j) {
        h[j] = __float2bfloat16(f[j]);
        l[j] = __float2bfloat16(f[j] - __bfloat162float(h[j]));
    }
    *(ushort4*)(Xh + i) = *(ushort4*)h;
    *(ushort4*)(Xl + i) = *(ushort4*)l;
}

// ----------------------- D = X2·X2^T fp32-accurate via 3-term split-bf16 MFMA
__global__ __launch_bounds__(256)
void k_gemm_d(const __hip_bfloat16* __restrict__ Xh,
              const __hip_bfloat16* __restrict__ Xl, float* __restrict__ D) {
    const int t = threadIdx.x;
    const int wave = t >> 6, lane = t & 63;
    const int quad = lane >> 4, l16 = lane & 15;
    const int bm = blockIdx.x * 128 + wave * 32;
    const int bn = blockIdx.y * 128;
    f32x4 acc[2][8] = {};
    for (int k0 = 0; k0 < CDIM; k0 += 32) {
        const int kq = k0 + quad * 8;
        bf16x8 ah[2], al[2], bh[8], bl[8];
        #pragma unroll
        for (int mi = 0; mi < 2; ++mi) {
            const size_t r = (size_t)(bm + mi * 16 + l16) * CDIM + kq;
            ah[mi] = *(const bf16x8*)(Xh + r);
            al[mi] = *(const bf16x8*)(Xl + r);
        }
        #pragma unroll
        for (int nf = 0; nf < 8; ++nf) {
            const size_t r = (size_t)(bn + nf * 16 + l16) * CDIM + kq;
            bh[nf] = *(const bf16x8*)(Xh + r);
            bl[nf] = *(const bf16x8*)(Xl + r);
        }
        #pragma unroll
        for (int mi = 0; mi < 2; ++mi)
            #pragma unroll
            for (int nf = 0; nf < 8; ++nf) {
                acc[mi][nf] = __builtin_amdgcn_mfma_f32_16x16x32_bf16(ah[mi], bh[nf], acc[mi][nf], 0, 0, 0);
                acc[mi][nf] = __builtin_amdgcn_mfma_f32_16x16x32_bf16(ah[mi], bl[nf], acc[mi][nf], 0, 0, 0);
                acc[mi][nf] = __builtin_amdgcn_mfma_f32_16x16x32_bf16(al[mi], bh[nf], acc[mi][nf], 0, 0, 0);
            }
    }
    #pragma unroll
    for (int mi = 0; mi < 2; ++mi)
        #pragma unroll
        for (int nf = 0; nf < 8; ++nf)
            #pragma unroll
            for (int r = 0; r < 4; ++r)
                D[(size_t)(bm + mi * 16 + quad * 4 + r) * LDIM + bn + nf * 16 + l16] = acc[mi][nf][r];
}

// ------------------------------------------------- invn[l] = 1/max(sqrt(.),eps)
__global__ void k_invnorm(const float* __restrict__ D, float* __restrict__ invn) {
    const int l = blockIdx.x * 256 + threadIdx.x;
    const int ly = l >> 6, lx = l & 63;
    float s = 0.f;
    #pragma unroll
    for (int ty = -1; ty <= 1; ++ty)
        #pragma unroll
        for (int tx = -1; tx <= 1; ++tx) {
            if ((unsigned)(ly + ty) < 64u && (unsigned)(lx + tx) < 64u) {
                const int q = l + ty * Ww + tx;
                s += D[(size_t)q * LDIM + q];
            }
        }
    invn[l] = 1.0f / fmaxf(sqrtf(s), 1e-4f);
}

// ---------------- G[x,l] = sum_t D[x+t,l+t], diagonal-run reuse (T=8)
__global__ __launch_bounds__(256)
void k_gdiag(const float* __restrict__ D, float* __restrict__ G) {
    constexpr int T = 8;
    const int l0 = blockIdx.x * 256 + threadIdx.x;
    const int x0 = blockIdx.y * T;
    const int xyc = x0 >> 6;
    const int xxb = x0 & 63;
    if (l0 <= LDIM - T) {
        float acc[T] = {};
        #pragma unroll
        for (int c = 0; c < 3; ++c) {
            const int bc = c * 64 - 65;          // -65, -1, 63
            const int ty = c - 1;
            const bool vyx = (unsigned)(xyc + ty) < 64u;
            float w[T + 2];
            #pragma unroll
            for (int u = 0; u < T + 2; ++u) {
                const int r  = x0 + bc + u;
                const int cc = l0 + bc + u;
                w[u] = ((unsigned)r < (unsigned)LDIM && (unsigned)cc < (unsigned)LDIM)
                         ? D[(size_t)r * LDIM + cc] : 0.f;
            }
            if (vyx) {
                #pragma unroll
                for (int i = 0; i < T; ++i) {
                    const int l = l0 + i;
                    const int ly = l >> 6, lx = l & 63;
                    if ((unsigned)(ly + ty) < 64u) {
                        const int xx = xxb + i;
                        if (xx > 0 && lx > 0)   acc[i] += w[i];
                        acc[i] += w[i + 1];
                        if (xx < 63 && lx < 63) acc[i] += w[i + 2];
                    }
                }
            }
        }
        #pragma unroll
        for (int i = 0; i < T; ++i)
            G[(size_t)(x0 + i) * LDIM + (l0 + i)] = acc[i];
    } else {
        for (int i = 0; i < T; ++i) {
            const int l = (l0 + i) & (LDIM - 1);
            const int ly = l >> 6, lx = l & 63;
            const int x = x0 + i;
            const int xy = x >> 6, xx = x & 63;
            float s = 0.f;
            #pragma unroll
            for (int ty = -1; ty <= 1; ++ty)
                #pragma unroll
                for (int tx = -1; tx <= 1; ++tx) {
                    if ((unsigned)(xy + ty) < 64u && (unsigned)(xx + tx) < 64u &&
                        (unsigned)(ly + ty) < 64u && (unsigned)(lx + tx) < 64u) {
                        const int off = ty * Ww + tx;
                        s += D[(size_t)(x + off) * LDIM + (l + off)];
                    }
                }
            G[(size_t)x * LDIM + l] = s;
        }
    }
}

// ------- P[x,l] = (90/cnt)*invn[l]*sum_s G[x+s,l]; vertical reuse + row stats
__global__ __launch_bounds__(256)
void k_pool_stats(const float* __restrict__ G, const float* __restrict__ invn,
                  float* __restrict__ Pout, float* __restrict__ rowm,
                  float* __restrict__ rowrz) {
    constexpr int T = 8;
    const int x0 = blockIdx.x * T;
    const int t  = threadIdx.x;
    const int xyc = x0 >> 6;
    const int xxb = x0 & 63;
    const int cy = 1 + (xyc > 0) + (xyc < 63);
    float sc[T];
    #pragma unroll
    for (int i = 0; i < T; ++i) {
        const int xx = xxb + i;
        sc[i] = 90.0f / (float)(cy * (1 + (xx > 0) + (xx < 63)));
    }
    float m[T], Z[T];
    #pragma unroll
    for (int i = 0; i < T; ++i) { m[i] = -1e30f; Z[i] = 0.f; }

    for (int ch = 0; ch < LDIM / 256; ++ch) {
        const int l = ch * 256 + t;
        const float inl = invn[l];
        float acc[T] = {};
        #pragma unroll
        for (int c = 0; c < 3; ++c) {
            const int bc = c * 64 - 65;
            const int ty = c - 1;
            float w[T + 2];
            #pragma unroll
            for (int u = 0; u < T + 2; ++u) {
                const int r = x0 + bc + u;
                w[u] = ((unsigned)r < (unsigned)LDIM) ? G[(size_t)r * LDIM + l] : 0.f;
            }
            if ((unsigned)(xyc + ty) < 64u) {
                #pragma unroll
                for (int i = 0; i < T; ++i) {
                    const int xx = xxb + i;
                    if (xx > 0)  acc[i] += w[i];
                    acc[i] += w[i + 1];
                    if (xx < 63) acc[i] += w[i + 2];
                }
            }
        }
        #pragma unroll
        for (int i = 0; i < T; ++i) {
            const float p = acc[i] * sc[i] * inl;
            Pout[(size_t)(x0 + i) * LDIM + l] = p;
            const float nm = fmaxf(m[i], p);
            Z[i] = Z[i] * __expf(m[i] - nm) + __expf(p - nm);
            m[i] = nm;
        }
    }
    __shared__ float sm[256], sz[256];
    for (int i = 0; i < T; ++i) {
        __syncthreads();
        sm[t] = m[i]; sz[t] = Z[i];
        __syncthreads();
        for (int off = 128; off > 0; off >>= 1) {
            if (t < off) {
                const float m2 = sm[t + off], z2 = sz[t + off];
                const float nm = fmaxf(sm[t], m2);
                sz[t] = sz[t] * __expf(sm[t] - nm) + z2 * __expf(m2 - nm);
                sm[t] = nm;
            }
            __syncthreads();
        }
        if (t == 0) { rowm[x0 + i] = sm[0]; rowrz[x0 + i] = 1.0f / sz[0]; }
    }
}

// ---- X1 [4096][128] fp32 -> X1T [128][4096] bf16 (LDS-tiled transpose)
__global__ __launch_bounds__(256)
void k_x1t(const float* __restrict__ X1, __hip_bfloat16* __restrict__ X1T) {
    __shared__ float tile[32][132];
    const int k0 = blockIdx.x * 32;
    const int t  = threadIdx.x;
    const int kr = t >> 3;
    const int c0 = (t & 7) * 16;
    #pragma unroll
    for (int j = 0; j < 4; ++j) {
        const float4 v = *(const float4*)(X1 + (size_t)(k0 + kr) * CDIM + c0 + 4 * j);
        tile[kr][c0 + 4 * j + 0] = v.x;
        tile[kr][c0 + 4 * j + 1] = v.y;
        tile[kr][c0 + 4 * j + 2] = v.z;
        tile[kr][c0 + 4 * j + 3] = v.w;
    }
    __syncthreads();
    const int c  = t >> 1;
    const int kh = (t & 1) * 16;
    __hip_bfloat16 outv[16];
    #pragma unroll
    for (int j = 0; j < 16; ++j)
        outv[j] = __float2bfloat16(tile[kh + j][c]);
    *(ushort4*)(X1T + (size_t)c * LDIM + k0 + kh)     = *(ushort4*)(outv);
    *(ushort4*)(X1T + (size_t)c * LDIM + k0 + kh + 4) = *(ushort4*)(outv + 4);
    *(ushort4*)(X1T + (size_t)c * LDIM + k0 + kh + 8) = *(ushort4*)(outv + 8);
    *(ushort4*)(X1T + (size_t)c * LDIM + k0 + kh + 12)= *(ushort4*)(outv + 12);
}

// ---- A2[p,q] = sum_t exp(P[p+t,q+t]-m)*rz; T=8 diag reuse; bf16 output
__global__ __launch_bounds__(256)
void k_att2(const float* __restrict__ P, const float* __restrict__ rowm,
            const float* __restrict__ rowrz, __hip_bfloat16* __restrict__ A2) {
    constexpr int T = 8;
    const int q0 = blockIdx.x * 256 + threadIdx.x;
    const int p0 = blockIdx.y * T;
    const int pyc = p0 >> 6;
    const int pxb = p0 & 63;
    if (q0 <= LDIM - T) {
        float acc[T] = {};
        #pragma unroll
        for (int c = 0; c < 3; ++c) {
            const int bc = c * 64 - 65;
            const int ty = c - 1;
            if ((unsigned)(pyc + ty) < 64u) {
                float e[T + 2];
                #pragma unroll
                for (int u = 0; u < T + 2; ++u) {
                    const int r  = p0 + bc + u;
                    const int cc = q0 + bc + u;
                    if ((unsigned)r < (unsigned)LDIM && (unsigned)cc < (unsigned)LDIM)
                        e[u] = __expf(P[(size_t)r * LDIM + cc] - rowm[r]) * rowrz[r];
                    else
                        e[u] = 0.f;
                }
                #pragma unroll
                for (int i = 0; i < T; ++i) {
                    const int q = q0 + i;
                    const int qy = q >> 6, qx = q & 63;
                    if ((unsigned)(qy + ty) < 64u) {
                        const int px = pxb + i;
                        if (px > 0 && qx > 0)   acc[i] += e[i];
                        acc[i] += e[i + 1];
                        if (px < 63 && qx < 63) acc[i] += e[i + 2];
                    }
                }
            }
        }
        #pragma unroll
        for (int i = 0; i < T; ++i)
            A2[(size_t)(p0 + i) * LDIM + (q0 + i)] = __float2bfloat16(acc[i]);
    } else {
        for (int i = 0; i < T; ++i) {
            const int q = (q0 + i) & (LDIM - 1);
            const int qy = q >> 6, qx = q & 63;
            const int p = p0 + i;
            const int py = p >> 6, px = p & 63;
            float s = 0.f;
            #pragma unroll
            for (int ty = -1; ty <= 1; ++ty)
                #pragma unroll
                for (int tx = -1; tx <= 1; ++tx) {
                    if ((unsigned)(py + ty) < 64u && (unsigned)(px + tx) < 64u &&
                        (unsigned)(qy + ty) < 64u && (unsigned)(qx + tx) < 64u) {
                        const int off = ty * Ww + tx;
                        const int u = p + off;
                        s += __expf(P[(size_t)u * LDIM + (q + off)] - rowm[u]) * rowrz[u];
                    }
                }
            A2[(size_t)p * LDIM + q] = __float2bfloat16(s);
        }
    }
}

// ---------------- Y += A2 @ X1 (bf16 MFMA, split-K=8, atomic f32 epilogue)
__global__ __launch_bounds__(256)
void k_gemm_y(const __hip_bfloat16* __restrict__ A2b,
              const __hip_bfloat16* __restrict__ X1T, float* __restrict__ Y) {
    const int t = threadIdx.x;
    const int wave = t >> 6, lane = t & 63;
    const int quad = lane >> 4, l16 = lane & 15;
    const int bm = blockIdx.x * 128 + wave * 32;
    const int kc = blockIdx.y * 512;
    f32x4 acc[2][8] = {};
    for (int ks = 0; ks < 512; ks += 32) {
        const int kq = kc + ks + quad * 8;
        bf16x8 a[2], b[8];
        #pragma unroll
        for (int mi = 0; mi < 2; ++mi)
            a[mi] = *(const bf16x8*)(A2b + (size_t)(bm + mi * 16 + l16) * LDIM + kq);
        #pragma unroll
        for (int nf = 0; nf < 8; ++nf)
            b[nf] = *(const bf16x8*)(X1T + (size_t)(nf * 16 + l16) * LDIM + kq);
        #pragma unroll
        for (int mi = 0; mi < 2; ++mi)
            #pragma unroll
            for (int nf = 0; nf < 8; ++nf)
                acc[mi][nf] = __builtin_amdgcn_mfma_f32_16x16x32_bf16(a[mi], b[nf], acc[mi][nf], 0, 0, 0);
    }
    #pragma unroll
    for (int mi = 0; mi < 2; ++mi)
        #pragma unroll
        for (int nf = 0; nf < 8; ++nf)
            #pragma unroll
            for (int r = 0; r < 4; ++r)
                atomicAdd(Y + (size_t)(bm + mi * 16 + quad * 4 + r) * CDIM + nf * 16 + l16,
                          acc[mi][nf][r]);
}

extern "C" void kernel_launch(void* const* d_in, const int* in_sizes, int n_in,
                              void* d_out, int out_size, void* d_ws, size_t ws_size,
                              hipStream_t stream) {
    const float* x1 = (const float*)d_in[0];
    const float* x2 = (const float*)d_in[1];
    float* out = (float*)d_out;

    const size_t MATB = (size_t)LDIM * LDIM * sizeof(float);   // 64 MB
    char* ws = (char*)d_ws;
    float* buf1  = (float*)ws;                         // D, then P (fp32)
    char*  buf2c = ws + MATB;                          // multi-use 64 MB
    float* buf2  = (float*)buf2c;                      // G (fp32)
    __hip_bfloat16* X2h = (__hip_bfloat16*)buf2c;                    // 1 MB
    __hip_bfloat16* X2l = (__hip_bfloat16*)(buf2c + (size_t)LDIM * CDIM * 2);
    __hip_bfloat16* A2b = (__hip_bfloat16*)buf2c;                    // 32 MB
    __hip_bfloat16* X1T = (__hip_bfloat16*)(buf2c + MATB / 2);       // 1 MB
    float* invn  = (float*)(ws + 2 * MATB);
    float* rowm  = invn + LDIM;
    float* rowrz = rowm + LDIM;

    const int B = in_sizes[0] / (LDIM * CDIM);

    hipMemsetAsync(d_out, 0, (size_t)out_size * sizeof(float), stream);

    for (int b = 0; b < B; ++b) {
        const float* X2b_ = x2 + (size_t)b * LDIM * CDIM;
        const float* X1b_ = x1 + (size_t)b * LDIM * CDIM;
        float* Yb = out + (size_t)b * LDIM * CDIM;

        k_split     <<<LDIM * CDIM / 1024, 256, 0, stream>>>(X2b_, X2h, X2l);
        k_gemm_d    <<<dim3(LDIM / 128, LDIM / 128), 256, 0, stream>>>(X2h, X2l, buf1);
        k_invnorm   <<<LDIM / 256, 256, 0, stream>>>(buf1, invn);
        k_gdiag     <<<dim3(LDIM / 256, LDIM / 8), 256, 0, stream>>>(buf1, buf2);
        k_pool_stats<<<LDIM / 8, 256, 0, stream>>>(buf2, invn, buf1, rowm, rowrz);
        k_x1t       <<<LDIM / 32, 256, 0, stream>>>(X1b_, X1T);
        k_att2      <<<dim3(LDIM / 256, LDIM / 8), 256, 0, stream>>>(buf1, rowm, rowrz, A2b);
        k_gemm_y    <<<dim3(LDIM / 128, 8), 256, 0, stream>>>(A2b, X1T, Yb);
    }
}

// Round 5
// 513.466 us; speedup vs baseline: 3.3548x; 1.1988x over previous
//
#include <hip/hip_runtime.h>
#include <hip/hip_bf16.h>
#include <math.h>

// AtnConv (contextual attention) B=2, H=W=64, C=128, k=3.
// Score path fp32: D = X2·X2^T (split-bf16 MFMA); invn; G = 9-tap diag
// stencil of D; P = pooled logits (stored DIAGONALLY SKEWED: Ps[x][(l-x)&4095])
// + row softmax stats. Value path bf16: A2 = diag stencil of softmax(P) read
// vertically from skewed Ps with float4 loads; Y = A2 @ X1 bf16 MFMA split-K.
// ws: buf1 (D->Ps) 64MB; buf2 (X2h/X2l -> G -> A2bf|X1T) 64MB; invn/rowm/rowrz.

constexpr int Hh = 64;
constexpr int Ww = 64;
constexpr int CDIM = 128;
constexpr int LDIM = Hh * Ww;   // 4096

typedef __attribute__((ext_vector_type(8))) short bf16x8;
typedef __attribute__((ext_vector_type(4))) float f32x4;

// --------------------------------------------- split X2 into bf16 hi/lo parts
__global__ __launch_bounds__(256)
void k_split(const float* __restrict__ X, __hip_bfloat16* __restrict__ Xh,
             __hip_bfloat16* __restrict__ Xl) {
    const int i = (blockIdx.x * 256 + threadIdx.x) * 4;
    const float4 v = *(const float4*)(X + i);
    __hip_bfloat16 h[4], l[4];
    const float f[4] = {v.x, v.y, v.z, v.w};
    #pragma unroll
    for (int j = 0; j < 4; ++j) {
        h[j] = __float2bfloat16(f[j]);
        l[j] = __float2bfloat16(f[j] - __bfloat162float(h[j]));
    }
    *(ushort4*)(Xh + i) = *(ushort4*)h;
    *(ushort4*)(Xl + i) = *(ushort4*)l;
}

// ----------------------- D = X2·X2^T fp32-accurate via 3-term split-bf16 MFMA
__global__ __launch_bounds__(256)
void k_gemm_d(const __hip_bfloat16* __restrict__ Xh,
              const __hip_bfloat16* __restrict__ Xl, float* __restrict__ D) {
    const int t = threadIdx.x;
    const int wave = t >> 6, lane = t & 63;
    const int quad = lane >> 4, l16 = lane & 15;
    const int bm = blockIdx.x * 128 + wave * 32;
    const int bn = blockIdx.y * 128;
    f32x4 acc[2][8] = {};
    for (int k0 = 0; k0 < CDIM; k0 += 32) {
        const int kq = k0 + quad * 8;
        bf16x8 ah[2], al[2], bh[8], bl[8];
        #pragma unroll
        for (int mi = 0; mi < 2; ++mi) {
            const size_t r = (size_t)(bm + mi * 16 + l16) * CDIM + kq;
            ah[mi] = *(const bf16x8*)(Xh + r);
            al[mi] = *(const bf16x8*)(Xl + r);
        }
        #pragma unroll
        for (int nf = 0; nf < 8; ++nf) {
            const size_t r = (size_t)(bn + nf * 16 + l16) * CDIM + kq;
            bh[nf] = *(const bf16x8*)(Xh + r);
            bl[nf] = *(const bf16x8*)(Xl + r);
        }
        #pragma unroll
        for (int mi = 0; mi < 2; ++mi)
            #pragma unroll
            for (int nf = 0; nf < 8; ++nf) {
                acc[mi][nf] = __builtin_amdgcn_mfma_f32_16x16x32_bf16(ah[mi], bh[nf], acc[mi][nf], 0, 0, 0);
                acc[mi][nf] = __builtin_amdgcn_mfma_f32_16x16x32_bf16(ah[mi], bl[nf], acc[mi][nf], 0, 0, 0);
                acc[mi][nf] = __builtin_amdgcn_mfma_f32_16x16x32_bf16(al[mi], bh[nf], acc[mi][nf], 0, 0, 0);
            }
    }
    #pragma unroll
    for (int mi = 0; mi < 2; ++mi)
        #pragma unroll
        for (int nf = 0; nf < 8; ++nf)
            #pragma unroll
            for (int r = 0; r < 4; ++r)
                D[(size_t)(bm + mi * 16 + quad * 4 + r) * LDIM + bn + nf * 16 + l16] = acc[mi][nf][r];
}

// ------------------------------------------------- invn[l] = 1/max(sqrt(.),eps)
__global__ void k_invnorm(const float* __restrict__ D, float* __restrict__ invn) {
    const int l = blockIdx.x * 256 + threadIdx.x;
    const int ly = l >> 6, lx = l & 63;
    float s = 0.f;
    #pragma unroll
    for (int ty = -1; ty <= 1; ++ty)
        #pragma unroll
        for (int tx = -1; tx <= 1; ++tx) {
            if ((unsigned)(ly + ty) < 64u && (unsigned)(lx + tx) < 64u) {
                const int q = l + ty * Ww + tx;
                s += D[(size_t)q * LDIM + q];
            }
        }
    invn[l] = 1.0f / fmaxf(sqrtf(s), 1e-4f);
}

// ---------------- G[x,l] = sum_t D[x+t,l+t], diagonal-run reuse (T=8)
__global__ __launch_bounds__(256)
void k_gdiag(const float* __restrict__ D, float* __restrict__ G) {
    constexpr int T = 8;
    const int l0 = blockIdx.x * 256 + threadIdx.x;
    const int x0 = blockIdx.y * T;
    const int xyc = x0 >> 6;
    const int xxb = x0 & 63;
    if (l0 <= LDIM - T) {
        float acc[T] = {};
        #pragma unroll
        for (int c = 0; c < 3; ++c) {
            const int bc = c * 64 - 65;          // -65, -1, 63
            const int ty = c - 1;
            const bool vyx = (unsigned)(xyc + ty) < 64u;
            float w[T + 2];
            #pragma unroll
            for (int u = 0; u < T + 2; ++u) {
                const int r  = x0 + bc + u;
                const int cc = l0 + bc + u;
                w[u] = ((unsigned)r < (unsigned)LDIM && (unsigned)cc < (unsigned)LDIM)
                         ? D[(size_t)r * LDIM + cc] : 0.f;
            }
            if (vyx) {
                #pragma unroll
                for (int i = 0; i < T; ++i) {
                    const int l = l0 + i;
                    const int ly = l >> 6, lx = l & 63;
                    if ((unsigned)(ly + ty) < 64u) {
                        const int xx = xxb + i;
                        if (xx > 0 && lx > 0)   acc[i] += w[i];
                        acc[i] += w[i + 1];
                        if (xx < 63 && lx < 63) acc[i] += w[i + 2];
                    }
                }
            }
        }
        #pragma unroll
        for (int i = 0; i < T; ++i)
            G[(size_t)(x0 + i) * LDIM + (l0 + i)] = acc[i];
    } else {
        for (int i = 0; i < T; ++i) {
            const int l = (l0 + i) & (LDIM - 1);
            const int ly = l >> 6, lx = l & 63;
            const int x = x0 + i;
            const int xy = x >> 6, xx = x & 63;
            float s = 0.f;
            #pragma unroll
            for (int ty = -1; ty <= 1; ++ty)
                #pragma unroll
                for (int tx = -1; tx <= 1; ++tx) {
                    if ((unsigned)(xy + ty) < 64u && (unsigned)(xx + tx) < 64u &&
                        (unsigned)(ly + ty) < 64u && (unsigned)(lx + tx) < 64u) {
                        const int off = ty * Ww + tx;
                        s += D[(size_t)(x + off) * LDIM + (l + off)];
                    }
                }
            G[(size_t)x * LDIM + l] = s;
        }
    }
}

// ------- P[x,l] = (90/cnt)*invn[l]*sum_s G[x+s,l]; 4-col float4 vectorized.
// Output stored SKEWED: Ps[x][(l-x)&4095] = P[x][l]. Row softmax stats too.
__global__ __launch_bounds__(256)
void k_pool_stats(const float* __restrict__ G, const float* __restrict__ invn,
                  float* __restrict__ Ps, float* __restrict__ rowm,
                  float* __restrict__ rowrz) {
    constexpr int T = 8;
    const int x0 = blockIdx.x * T;
    const int t  = threadIdx.x;
    const int xyc = x0 >> 6;
    const int xxb = x0 & 63;
    const int cy = 1 + (xyc > 0) + (xyc < 63);
    float sc[T];
    #pragma unroll
    for (int i = 0; i < T; ++i) {
        const int xx = xxb + i;
        sc[i] = 90.0f / (float)(cy * (1 + (xx > 0) + (xx < 63)));
    }
    float m[T], Z[T];
    #pragma unroll
    for (int i = 0; i < T; ++i) { m[i] = -1e30f; Z[i] = 0.f; }

    for (int ch = 0; ch < 4; ++ch) {
        const int l0 = ch * 1024 + t * 4;
        const f32x4 inl = *(const f32x4*)(invn + l0);
        f32x4 acc[T];
        #pragma unroll
        for (int i = 0; i < T; ++i) acc[i] = (f32x4){0.f, 0.f, 0.f, 0.f};
        #pragma unroll
        for (int c = 0; c < 3; ++c) {
            const int bc = c * 64 - 65;
            const int ty = c - 1;
            if ((unsigned)(xyc + ty) >= 64u) continue;
            f32x4 w[T + 2];
            #pragma unroll
            for (int u = 0; u < T + 2; ++u) {
                const int r = x0 + bc + u;
                w[u] = ((unsigned)r < (unsigned)LDIM)
                         ? *(const f32x4*)(G + (size_t)r * LDIM + l0)
                         : (f32x4){0.f, 0.f, 0.f, 0.f};
            }
            #pragma unroll
            for (int i = 0; i < T; ++i) {
                const int xx = xxb + i;
                if (xx > 0)  acc[i] += w[i];
                acc[i] += w[i + 1];
                if (xx < 63) acc[i] += w[i + 2];
            }
        }
        #pragma unroll
        for (int i = 0; i < T; ++i) {
            const f32x4 p = acc[i] * sc[i] * inl;
            const int x = x0 + i;
            const int c0 = (l0 - x) & (LDIM - 1);
            float* base = Ps + (size_t)x * LDIM;
            if (c0 <= LDIM - 4) {
                if (!(i & 1)) {   // c0 even -> 8B aligned pairs
                    *(float2*)(base + c0)     = make_float2(p.x, p.y);
                    *(float2*)(base + c0 + 2) = make_float2(p.z, p.w);
                } else {          // c0 odd -> c0+1 even
                    base[c0] = p.x;
                    *(float2*)(base + c0 + 1) = make_float2(p.y, p.z);
                    base[c0 + 3] = p.w;
                }
            } else {
                base[c0] = p.x;
                base[(c0 + 1) & (LDIM - 1)] = p.y;
                base[(c0 + 2) & (LDIM - 1)] = p.z;
                base[(c0 + 3) & (LDIM - 1)] = p.w;
            }
            const float mx4 = fmaxf(fmaxf(p.x, p.y), fmaxf(p.z, p.w));
            const float nm = fmaxf(m[i], mx4);
            Z[i] = Z[i] * __expf(m[i] - nm)
                 + __expf(p.x - nm) + __expf(p.y - nm)
                 + __expf(p.z - nm) + __expf(p.w - nm);
            m[i] = nm;
        }
    }
    __shared__ float sm[256], sz[256];
    for (int i = 0; i < T; ++i) {
        __syncthreads();
        sm[t] = m[i]; sz[t] = Z[i];
        __syncthreads();
        for (int off = 128; off > 0; off >>= 1) {
            if (t < off) {
                const float m2 = sm[t + off], z2 = sz[t + off];
                const float nm = fmaxf(sm[t], m2);
                sz[t] = sz[t] * __expf(sm[t] - nm) + z2 * __expf(m2 - nm);
                sm[t] = nm;
            }
            __syncthreads();
        }
        if (t == 0) { rowm[x0 + i] = sm[0]; rowrz[x0 + i] = 1.0f / sz[0]; }
    }
}

// ---- X1 [4096][128] fp32 -> X1T [128][4096] bf16 (LDS-tiled transpose)
__global__ __launch_bounds__(256)
void k_x1t(const float* __restrict__ X1, __hip_bfloat16* __restrict__ X1T) {
    __shared__ float tile[32][132];
    const int k0 = blockIdx.x * 32;
    const int t  = threadIdx.x;
    const int kr = t >> 3;
    const int c0 = (t & 7) * 16;
    #pragma unroll
    for (int j = 0; j < 4; ++j) {
        const float4 v = *(const float4*)(X1 + (size_t)(k0 + kr) * CDIM + c0 + 4 * j);
        tile[kr][c0 + 4 * j + 0] = v.x;
        tile[kr][c0 + 4 * j + 1] = v.y;
        tile[kr][c0 + 4 * j + 2] = v.z;
        tile[kr][c0 + 4 * j + 3] = v.w;
    }
    __syncthreads();
    const int c  = t >> 1;
    const int kh = (t & 1) * 16;
    __hip_bfloat16 outv[16];
    #pragma unroll
    for (int j = 0; j < 16; ++j)
        outv[j] = __float2bfloat16(tile[kh + j][c]);
    *(ushort4*)(X1T + (size_t)c * LDIM + k0 + kh)     = *(ushort4*)(outv);
    *(ushort4*)(X1T + (size_t)c * LDIM + k0 + kh + 4) = *(ushort4*)(outv + 4);
    *(ushort4*)(X1T + (size_t)c * LDIM + k0 + kh + 8) = *(ushort4*)(outv + 8);
    *(ushort4*)(X1T + (size_t)c * LDIM + k0 + kh + 12)= *(ushort4*)(outv + 12);
}

// ---- A2[p,q] = sum_t exp(P[p+t,q+t]-m)*rz. Reads skewed Ps vertically:
// thread owns 4 diagonals d0..d0+3 x T rows; aligned float4 loads; shared exps.
__global__ __launch_bounds__(256)
void k_att2(const float* __restrict__ Ps, const float* __restrict__ rowm,
            const float* __restrict__ rowrz, __hip_bfloat16* __restrict__ A2) {
    constexpr int T = 8;
    const int d0 = (blockIdx.x * 256 + threadIdx.x) * 4;
    const int p0 = blockIdx.y * T;
    const int pyc = p0 >> 6;
    const int pxb = p0 & 63;
    float acc[T][4] = {};
    #pragma unroll
    for (int c = 0; c < 3; ++c) {
        const int bc = c * 64 - 65;          // -65, -1, 63
        const int ty = c - 1;
        if ((unsigned)(pyc + ty) >= 64u) continue;
        float e[T + 2][4];
        #pragma unroll
        for (int u = 0; u < T + 2; ++u) {
            const int r = p0 + bc + u;
            if ((unsigned)r < (unsigned)LDIM) {
                const f32x4 w = *(const f32x4*)(Ps + (size_t)r * LDIM + d0);
                const float mr = rowm[r], rzr = rowrz[r];
                e[u][0] = __expf(w.x - mr) * rzr;
                e[u][1] = __expf(w.y - mr) * rzr;
                e[u][2] = __expf(w.z - mr) * rzr;
                e[u][3] = __expf(w.w - mr) * rzr;
            } else {
                e[u][0] = e[u][1] = e[u][2] = e[u][3] = 0.f;
            }
        }
        #pragma unroll
        for (int i = 0; i < T; ++i) {
            const int px = pxb + i;
            const int p  = p0 + i;
            #pragma unroll
            for (int j = 0; j < 4; ++j) {
                const int q  = (p + d0 + j) & (LDIM - 1);
                const int qy = q >> 6, qx = q & 63;
                if ((unsigned)(qy + ty) < 64u) {
                    float s = acc[i][j];
                    if (px > 0 && qx > 0)   s += e[i][j];
                    s += e[i + 1][j];
                    if (px < 63 && qx < 63) s += e[i + 2][j];
                    acc[i][j] = s;
                }
            }
        }
    }
    #pragma unroll
    for (int i = 0; i < T; ++i) {
        const int p = p0 + i;
        const int q0i = (p + d0) & (LDIM - 1);
        union { __hip_bfloat16 h[4]; unsigned short us[4]; unsigned int ui[2]; } cv;
        #pragma unroll
        for (int j = 0; j < 4; ++j) cv.h[j] = __float2bfloat16(acc[i][j]);
        unsigned short* bp = (unsigned short*)(A2 + (size_t)p * LDIM);
        if (q0i <= LDIM - 4) {
            if (!(i & 1)) {   // q0i even -> 4B-aligned dword pairs
                *(unsigned int*)(bp + q0i)     = cv.ui[0];
                *(unsigned int*)(bp + q0i + 2) = cv.ui[1];
            } else {          // q0i odd -> q0i+1 even
                bp[q0i] = cv.us[0];
                *(unsigned int*)(bp + q0i + 1) =
                    (unsigned int)cv.us[1] | ((unsigned int)cv.us[2] << 16);
                bp[q0i + 3] = cv.us[3];
            }
        } else {
            #pragma unroll
            for (int j = 0; j < 4; ++j)
                bp[(q0i + j) & (LDIM - 1)] = cv.us[j];
        }
    }
}

// ---------------- Y += A2 @ X1 (bf16 MFMA, split-K=8, atomic f32 epilogue)
__global__ __launch_bounds__(256)
void k_gemm_y(const __hip_bfloat16* __restrict__ A2b,
              const __hip_bfloat16* __restrict__ X1T, float* __restrict__ Y) {
    const int t = threadIdx.x;
    const int wave = t >> 6, lane = t & 63;
    const int quad = lane >> 4, l16 = lane & 15;
    const int bm = blockIdx.x * 128 + wave * 32;
    const int kc = blockIdx.y * 512;
    f32x4 acc[2][8] = {};
    for (int ks = 0; ks < 512; ks += 32) {
        const int kq = kc + ks + quad * 8;
        bf16x8 a[2], b[8];
        #pragma unroll
        for (int mi = 0; mi < 2; ++mi)
            a[mi] = *(const bf16x8*)(A2b + (size_t)(bm + mi * 16 + l16) * LDIM + kq);
        #pragma unroll
        for (int nf = 0; nf < 8; ++nf)
            b[nf] = *(const bf16x8*)(X1T + (size_t)(nf * 16 + l16) * LDIM + kq);
        #pragma unroll
        for (int mi = 0; mi < 2; ++mi)
            #pragma unroll
            for (int nf = 0; nf < 8; ++nf)
                acc[mi][nf] = __builtin_amdgcn_mfma_f32_16x16x32_bf16(a[mi], b[nf], acc[mi][nf], 0, 0, 0);
    }
    #pragma unroll
    for (int mi = 0; mi < 2; ++mi)
        #pragma unroll
        for (int nf = 0; nf < 8; ++nf)
            #pragma unroll
            for (int r = 0; r < 4; ++r)
                atomicAdd(Y + (size_t)(bm + mi * 16 + quad * 4 + r) * CDIM + nf * 16 + l16,
                          acc[mi][nf][r]);
}

extern "C" void kernel_launch(void* const* d_in, const int* in_sizes, int n_in,
                              void* d_out, int out_size, void* d_ws, size_t ws_size,
                              hipStream_t stream) {
    const float* x1 = (const float*)d_in[0];
    const float* x2 = (const float*)d_in[1];
    float* out = (float*)d_out;

    const size_t MATB = (size_t)LDIM * LDIM * sizeof(float);   // 64 MB
    char* ws = (char*)d_ws;
    float* buf1  = (float*)ws;                         // D, then Ps (fp32)
    char*  buf2c = ws + MATB;                          // multi-use 64 MB
    float* buf2  = (float*)buf2c;                      // G (fp32)
    __hip_bfloat16* X2h = (__hip_bfloat16*)buf2c;                    // 1 MB
    __hip_bfloat16* X2l = (__hip_bfloat16*)(buf2c + (size_t)LDIM * CDIM * 2);
    __hip_bfloat16* A2b = (__hip_bfloat16*)buf2c;                    // 32 MB
    __hip_bfloat16* X1T = (__hip_bfloat16*)(buf2c + MATB / 2);       // 1 MB
    float* invn  = (float*)(ws + 2 * MATB);
    float* rowm  = invn + LDIM;
    float* rowrz = rowm + LDIM;

    const int B = in_sizes[0] / (LDIM * CDIM);

    hipMemsetAsync(d_out, 0, (size_t)out_size * sizeof(float), stream);

    for (int b = 0; b < B; ++b) {
        const float* X2b_ = x2 + (size_t)b * LDIM * CDIM;
        const float* X1b_ = x1 + (size_t)b * LDIM * CDIM;
        float* Yb = out + (size_t)b * LDIM * CDIM;

        k_split     <<<LDIM * CDIM / 1024, 256, 0, stream>>>(X2b_, X2h, X2l);
        k_gemm_d    <<<dim3(LDIM / 128, LDIM / 128), 256, 0, stream>>>(X2h, X2l, buf1);
        k_invnorm   <<<LDIM / 256, 256, 0, stream>>>(buf1, invn);
        k_gdiag     <<<dim3(LDIM / 256, LDIM / 8), 256, 0, stream>>>(buf1, buf2);
        k_pool_stats<<<LDIM / 8, 256, 0, stream>>>(buf2, invn, buf1, rowm, rowrz);
        k_x1t       <<<LDIM / 32, 256, 0, stream>>>(X1b_, X1T);
        k_att2      <<<dim3(LDIM / 1024, LDIM / 8), 256, 0, stream>>>(buf1, rowm, rowrz, A2b);
        k_gemm_y    <<<dim3(LDIM / 128, 8), 256, 0, stream>>>(A2b, X1T, Yb);
    }
}

// Round 7
// 481.354 us; speedup vs baseline: 3.5787x; 1.0667x over previous
//
#include <hip/hip_runtime.h>
#include <hip/hip_bf16.h>
#include <math.h>

// AtnConv (contextual attention) B=2, H=W=64, C=128, k=3.
// Score path fp32: Ds = skewed X2·X2^T (split-bf16 MFMA, Ds[r][(c-r)&4095]);
// invn from skewed col 0; G = 9-tap diag stencil read VERTICALLY from Ds
// (float4, T=8 rows x 4 diagonals/thread); Ps = pooled logits (skewed) + row
// softmax stats. Value path bf16: A2 = diag stencil of softmax(Ps) (vertical
// float4 reads); Y = A2 @ X1 bf16 MFMA split-K.
// ws: buf1 (Ds->Ps) 64MB; buf2 (X2h/X2l -> G -> A2bf|X1T) 64MB; invn/rowm/rowrz.
// NOTE: k_x1t MUST run after k_pool_stats — X1T at buf2+32MB is clobbered by G.

constexpr int Hh = 64;
constexpr int Ww = 64;
constexpr int CDIM = 128;
constexpr int LDIM = Hh * Ww;   // 4096

typedef __attribute__((ext_vector_type(8))) short bf16x8;
typedef __attribute__((ext_vector_type(4))) float f32x4;

// --------------------------------------------- split X2 into bf16 hi/lo parts
__global__ __launch_bounds__(256)
void k_split(const float* __restrict__ X, __hip_bfloat16* __restrict__ Xh,
             __hip_bfloat16* __restrict__ Xl) {
    const int i = (blockIdx.x * 256 + threadIdx.x) * 4;
    const float4 v = *(const float4*)(X + i);
    __hip_bfloat16 h[4], l[4];
    const float f[4] = {v.x, v.y, v.z, v.w};
    #pragma unroll
    for (int j = 0; j < 4; ++j) {
        h[j] = __float2bfloat16(f[j]);
        l[j] = __float2bfloat16(f[j] - __bfloat162float(h[j]));
    }
    *(ushort4*)(Xh + i) = *(ushort4*)h;
    *(ushort4*)(Xl + i) = *(ushort4*)l;
}

// -------- Ds = skewed X2·X2^T via 3-term split-bf16 MFMA; Ds[r][(c-r)&4095]
__global__ __launch_bounds__(256)
void k_gemm_d(const __hip_bfloat16* __restrict__ Xh,
              const __hip_bfloat16* __restrict__ Xl, float* __restrict__ Ds) {
    const int t = threadIdx.x;
    const int wave = t >> 6, lane = t & 63;
    const int quad = lane >> 4, l16 = lane & 15;
    const int bm = blockIdx.x * 128 + wave * 32;
    const int bn = blockIdx.y * 128;
    f32x4 acc[2][8] = {};
    for (int k0 = 0; k0 < CDIM; k0 += 32) {
        const int kq = k0 + quad * 8;
        bf16x8 ah[2], al[2], bh[8], bl[8];
        #pragma unroll
        for (int mi = 0; mi < 2; ++mi) {
            const size_t r = (size_t)(bm + mi * 16 + l16) * CDIM + kq;
            ah[mi] = *(const bf16x8*)(Xh + r);
            al[mi] = *(const bf16x8*)(Xl + r);
        }
        #pragma unroll
        for (int nf = 0; nf < 8; ++nf) {
            const size_t r = (size_t)(bn + nf * 16 + l16) * CDIM + kq;
            bh[nf] = *(const bf16x8*)(Xh + r);
            bl[nf] = *(const bf16x8*)(Xl + r);
        }
        #pragma unroll
        for (int mi = 0; mi < 2; ++mi)
            #pragma unroll
            for (int nf = 0; nf < 8; ++nf) {
                acc[mi][nf] = __builtin_amdgcn_mfma_f32_16x16x32_bf16(ah[mi], bh[nf], acc[mi][nf], 0, 0, 0);
                acc[mi][nf] = __builtin_amdgcn_mfma_f32_16x16x32_bf16(ah[mi], bl[nf], acc[mi][nf], 0, 0, 0);
                acc[mi][nf] = __builtin_amdgcn_mfma_f32_16x16x32_bf16(al[mi], bh[nf], acc[mi][nf], 0, 0, 0);
            }
    }
    #pragma unroll
    for (int mi = 0; mi < 2; ++mi)
        #pragma unroll
        for (int nf = 0; nf < 8; ++nf) {
            const int row = bm + mi * 16 + quad * 4;
            const int col = bn + nf * 16 + l16;
            #pragma unroll
            for (int r = 0; r < 4; ++r)
                Ds[(size_t)(row + r) * LDIM + ((col - row - r) & (LDIM - 1))] = acc[mi][nf][r];
        }
}

// ---------------- invn[l] = 1/max(sqrt(sum diag-neigh),eps); diag = Ds[.][0]
__global__ void k_invnorm(const float* __restrict__ Ds, float* __restrict__ invn) {
    const int l = blockIdx.x * 256 + threadIdx.x;
    const int ly = l >> 6, lx = l & 63;
    float s = 0.f;
    #pragma unroll
    for (int ty = -1; ty <= 1; ++ty)
        #pragma unroll
        for (int tx = -1; tx <= 1; ++tx) {
            if ((unsigned)(ly + ty) < 64u && (unsigned)(lx + tx) < 64u) {
                const int q = l + ty * Ww + tx;
                s += Ds[(size_t)q * LDIM];
            }
        }
    invn[l] = 1.0f / fmaxf(sqrtf(s), 1e-4f);
}

// ---- G[x,l] = sum_t D[x+t,l+t] read vertically from skewed Ds.
// Thread: 4 diagonals d0..d0+3 x T=8 rows; aligned float4 loads; G normal layout.
__global__ __launch_bounds__(256)
void k_gdiag(const float* __restrict__ Ds, float* __restrict__ G) {
    constexpr int T = 8;
    const int d0 = (blockIdx.x * 256 + threadIdx.x) * 4;
    const int x0 = blockIdx.y * T;
    const int xyc = x0 >> 6;
    const int xxb = x0 & 63;
    float acc[T][4] = {};
    #pragma unroll
    for (int c = 0; c < 3; ++c) {
        const int bc = c * 64 - 65;          // -65, -1, 63
        const int ty = c - 1;
        if ((unsigned)(xyc + ty) >= 64u) continue;
        float w[T + 2][4];
        #pragma unroll
        for (int u = 0; u < T + 2; ++u) {
            const int r = x0 + bc + u;
            if ((unsigned)r < (unsigned)LDIM) {
                const f32x4 v = *(const f32x4*)(Ds + (size_t)r * LDIM + d0);
                w[u][0] = v.x; w[u][1] = v.y; w[u][2] = v.z; w[u][3] = v.w;
            } else {
                w[u][0] = w[u][1] = w[u][2] = w[u][3] = 0.f;
            }
        }
        #pragma unroll
        for (int i = 0; i < T; ++i) {
            const int px = xxb + i;
            const int p  = x0 + i;
            #pragma unroll
            for (int j = 0; j < 4; ++j) {
                const int l  = (p + d0 + j) & (LDIM - 1);
                const int ly = l >> 6, lx = l & 63;
                if ((unsigned)(ly + ty) < 64u) {
                    float s = acc[i][j];
                    if (px > 0 && lx > 0)   s += w[i][j];
                    s += w[i + 1][j];
                    if (px < 63 && lx < 63) s += w[i + 2][j];
                    acc[i][j] = s;
                }
            }
        }
    }
    #pragma unroll
    for (int i = 0; i < T; ++i) {
        const int x = x0 + i;
        const int l0i = (x + d0) & (LDIM - 1);
        float* base = G + (size_t)x * LDIM;
        if (l0i <= LDIM - 4) {
            if (!(l0i & 1)) {
                *(float2*)(base + l0i)     = make_float2(acc[i][0], acc[i][1]);
                *(float2*)(base + l0i + 2) = make_float2(acc[i][2], acc[i][3]);
            } else {
                base[l0i] = acc[i][0];
                *(float2*)(base + l0i + 1) = make_float2(acc[i][1], acc[i][2]);
                base[l0i + 3] = acc[i][3];
            }
        } else {
            #pragma unroll
            for (int j = 0; j < 4; ++j)
                base[(l0i + j) & (LDIM - 1)] = acc[i][j];
        }
    }
}

// ------- P[x,l] = (90/cnt)*invn[l]*sum_s G[x+s,l]; 4-col float4 vectorized.
// Output stored SKEWED: Ps[x][(l-x)&4095] = P[x][l]. Row softmax stats too.
__global__ __launch_bounds__(256)
void k_pool_stats(const float* __restrict__ G, const float* __restrict__ invn,
                  float* __restrict__ Ps, float* __restrict__ rowm,
                  float* __restrict__ rowrz) {
    constexpr int T = 8;
    const int x0 = blockIdx.x * T;
    const int t  = threadIdx.x;
    const int xyc = x0 >> 6;
    const int xxb = x0 & 63;
    const int cy = 1 + (xyc > 0) + (xyc < 63);
    float sc[T];
    #pragma unroll
    for (int i = 0; i < T; ++i) {
        const int xx = xxb + i;
        sc[i] = 90.0f / (float)(cy * (1 + (xx > 0) + (xx < 63)));
    }
    float m[T], Z[T];
    #pragma unroll
    for (int i = 0; i < T; ++i) { m[i] = -1e30f; Z[i] = 0.f; }

    for (int ch = 0; ch < 4; ++ch) {
        const int l0 = ch * 1024 + t * 4;
        const f32x4 inl = *(const f32x4*)(invn + l0);
        f32x4 acc[T];
        #pragma unroll
        for (int i = 0; i < T; ++i) acc[i] = (f32x4){0.f, 0.f, 0.f, 0.f};
        #pragma unroll
        for (int c = 0; c < 3; ++c) {
            const int bc = c * 64 - 65;
            const int ty = c - 1;
            if ((unsigned)(xyc + ty) >= 64u) continue;
            f32x4 w[T + 2];
            #pragma unroll
            for (int u = 0; u < T + 2; ++u) {
                const int r = x0 + bc + u;
                w[u] = ((unsigned)r < (unsigned)LDIM)
                         ? *(const f32x4*)(G + (size_t)r * LDIM + l0)
                         : (f32x4){0.f, 0.f, 0.f, 0.f};
            }
            #pragma unroll
            for (int i = 0; i < T; ++i) {
                const int xx = xxb + i;
                if (xx > 0)  acc[i] += w[i];
                acc[i] += w[i + 1];
                if (xx < 63) acc[i] += w[i + 2];
            }
        }
        #pragma unroll
        for (int i = 0; i < T; ++i) {
            const f32x4 p = acc[i] * sc[i] * inl;
            const int x = x0 + i;
            const int c0 = (l0 - x) & (LDIM - 1);
            float* base = Ps + (size_t)x * LDIM;
            if (c0 <= LDIM - 4) {
                if (!(c0 & 1)) {
                    *(float2*)(base + c0)     = make_float2(p.x, p.y);
                    *(float2*)(base + c0 + 2) = make_float2(p.z, p.w);
                } else {
                    base[c0] = p.x;
                    *(float2*)(base + c0 + 1) = make_float2(p.y, p.z);
                    base[c0 + 3] = p.w;
                }
            } else {
                base[c0] = p.x;
                base[(c0 + 1) & (LDIM - 1)] = p.y;
                base[(c0 + 2) & (LDIM - 1)] = p.z;
                base[(c0 + 3) & (LDIM - 1)] = p.w;
            }
            const float mx4 = fmaxf(fmaxf(p.x, p.y), fmaxf(p.z, p.w));
            const float nm = fmaxf(m[i], mx4);
            Z[i] = Z[i] * __expf(m[i] - nm)
                 + __expf(p.x - nm) + __expf(p.y - nm)
                 + __expf(p.z - nm) + __expf(p.w - nm);
            m[i] = nm;
        }
    }
    __shared__ float sm[256], sz[256];
    for (int i = 0; i < T; ++i) {
        __syncthreads();
        sm[t] = m[i]; sz[t] = Z[i];
        __syncthreads();
        for (int off = 128; off > 0; off >>= 1) {
            if (t < off) {
                const float m2 = sm[t + off], z2 = sz[t + off];
                const float nm = fmaxf(sm[t], m2);
                sz[t] = sz[t] * __expf(sm[t] - nm) + z2 * __expf(m2 - nm);
                sm[t] = nm;
            }
            __syncthreads();
        }
        if (t == 0) { rowm[x0 + i] = sm[0]; rowrz[x0 + i] = 1.0f / sz[0]; }
    }
}

// ---- X1 [4096][128] fp32 -> X1T [128][4096] bf16 (LDS-tiled transpose)
// Launched AFTER k_pool_stats: X1T region overlaps G's tail in buf2.
__global__ __launch_bounds__(256)
void k_x1t(const float* __restrict__ X1, __hip_bfloat16* __restrict__ X1T) {
    __shared__ float tile[32][132];
    const int k0 = blockIdx.x * 32;
    const int t  = threadIdx.x;
    const int kr = t >> 3;
    const int c0 = (t & 7) * 16;
    #pragma unroll
    for (int j = 0; j < 4; ++j) {
        const float4 v = *(const float4*)(X1 + (size_t)(k0 + kr) * CDIM + c0 + 4 * j);
        tile[kr][c0 + 4 * j + 0] = v.x;
        tile[kr][c0 + 4 * j + 1] = v.y;
        tile[kr][c0 + 4 * j + 2] = v.z;
        tile[kr][c0 + 4 * j + 3] = v.w;
    }
    __syncthreads();
    const int c  = t >> 1;
    const int kh = (t & 1) * 16;
    __hip_bfloat16 outv[16];
    #pragma unroll
    for (int j = 0; j < 16; ++j)
        outv[j] = __float2bfloat16(tile[kh + j][c]);
    *(ushort4*)(X1T + (size_t)c * LDIM + k0 + kh)      = *(ushort4*)(outv);
    *(ushort4*)(X1T + (size_t)c * LDIM + k0 + kh + 4)  = *(ushort4*)(outv + 4);
    *(ushort4*)(X1T + (size_t)c * LDIM + k0 + kh + 8)  = *(ushort4*)(outv + 8);
    *(ushort4*)(X1T + (size_t)c * LDIM + k0 + kh + 12) = *(ushort4*)(outv + 12);
}

// ---- A2[p,q] = sum_t exp(P[p+t,q+t]-m)*rz. Reads skewed Ps vertically.
__global__ __launch_bounds__(256)
void k_att2(const float* __restrict__ Ps, const float* __restrict__ rowm,
            const float* __restrict__ rowrz, __hip_bfloat16* __restrict__ A2) {
    constexpr int T = 8;
    const int d0 = (blockIdx.x * 256 + threadIdx.x) * 4;
    const int p0 = blockIdx.y * T;
    const int pyc = p0 >> 6;
    const int pxb = p0 & 63;
    float acc[T][4] = {};
    #pragma unroll
    for (int c = 0; c < 3; ++c) {
        const int bc = c * 64 - 65;          // -65, -1, 63
        const int ty = c - 1;
        if ((unsigned)(pyc + ty) >= 64u) continue;
        float e[T + 2][4];
        #pragma unroll
        for (int u = 0; u < T + 2; ++u) {
            const int r = p0 + bc + u;
            if ((unsigned)r < (unsigned)LDIM) {
                const f32x4 w = *(const f32x4*)(Ps + (size_t)r * LDIM + d0);
                const float mr = rowm[r], rzr = rowrz[r];
                e[u][0] = __expf(w.x - mr) * rzr;
                e[u][1] = __expf(w.y - mr) * rzr;
                e[u][2] = __expf(w.z - mr) * rzr;
                e[u][3] = __expf(w.w - mr) * rzr;
            } else {
                e[u][0] = e[u][1] = e[u][2] = e[u][3] = 0.f;
            }
        }
        #pragma unroll
        for (int i = 0; i < T; ++i) {
            const int px = pxb + i;
            const int p  = p0 + i;
            #pragma unroll
            for (int j = 0; j < 4; ++j) {
                const int q  = (p + d0 + j) & (LDIM - 1);
                const int qy = q >> 6, qx = q & 63;
                if ((unsigned)(qy + ty) < 64u) {
                    float s = acc[i][j];
                    if (px > 0 && qx > 0)   s += e[i][j];
                    s += e[i + 1][j];
                    if (px < 63 && qx < 63) s += e[i + 2][j];
                    acc[i][j] = s;
                }
            }
        }
    }
    #pragma unroll
    for (int i = 0; i < T; ++i) {
        const int p = p0 + i;
        const int q0i = (p + d0) & (LDIM - 1);
        union { __hip_bfloat16 h[4]; unsigned short us[4]; unsigned int ui[2]; } cv;
        #pragma unroll
        for (int j = 0; j < 4; ++j) cv.h[j] = __float2bfloat16(acc[i][j]);
        unsigned short* bp = (unsigned short*)(A2 + (size_t)p * LDIM);
        if (q0i <= LDIM - 4) {
            if (!(q0i & 1)) {
                *(unsigned int*)(bp + q0i)     = cv.ui[0];
                *(unsigned int*)(bp + q0i + 2) = cv.ui[1];
            } else {
                bp[q0i] = cv.us[0];
                *(unsigned int*)(bp + q0i + 1) =
                    (unsigned int)cv.us[1] | ((unsigned int)cv.us[2] << 16);
                bp[q0i + 3] = cv.us[3];
            }
        } else {
            #pragma unroll
            for (int j = 0; j < 4; ++j)
                bp[(q0i + j) & (LDIM - 1)] = cv.us[j];
        }
    }
}

// ---------------- Y += A2 @ X1 (bf16 MFMA, split-K=8, atomic f32 epilogue)
__global__ __launch_bounds__(256)
void k_gemm_y(const __hip_bfloat16* __restrict__ A2b,
              const __hip_bfloat16* __restrict__ X1T, float* __restrict__ Y) {
    const int t = threadIdx.x;
    const int wave = t >> 6, lane = t & 63;
    const int quad = lane >> 4, l16 = lane & 15;
    const int bm = blockIdx.x * 128 + wave * 32;
    const int kc = blockIdx.y * 512;
    f32x4 acc[2][8] = {};
    for (int ks = 0; ks < 512; ks += 32) {
        const int kq = kc + ks + quad * 8;
        bf16x8 a[2], b[8];
        #pragma unroll
        for (int mi = 0; mi < 2; ++mi)
            a[mi] = *(const bf16x8*)(A2b + (size_t)(bm + mi * 16 + l16) * LDIM + kq);
        #pragma unroll
        for (int nf = 0; nf < 8; ++nf)
            b[nf] = *(const bf16x8*)(X1T + (size_t)(nf * 16 + l16) * LDIM + kq);
        #pragma unroll
        for (int mi = 0; mi < 2; ++mi)
            #pragma unroll
            for (int nf = 0; nf < 8; ++nf)
                acc[mi][nf] = __builtin_amdgcn_mfma_f32_16x16x32_bf16(a[mi], b[nf], acc[mi][nf], 0, 0, 0);
    }
    #pragma unroll
    for (int mi = 0; mi < 2; ++mi)
        #pragma unroll
        for (int nf = 0; nf < 8; ++nf)
            #pragma unroll
            for (int r = 0; r < 4; ++r)
                atomicAdd(Y + (size_t)(bm + mi * 16 + quad * 4 + r) * CDIM + nf * 16 + l16,
                          acc[mi][nf][r]);
}

extern "C" void kernel_launch(void* const* d_in, const int* in_sizes, int n_in,
                              void* d_out, int out_size, void* d_ws, size_t ws_size,
                              hipStream_t stream) {
    const float* x1 = (const float*)d_in[0];
    const float* x2 = (const float*)d_in[1];
    float* out = (float*)d_out;

    const size_t MATB = (size_t)LDIM * LDIM * sizeof(float);   // 64 MB
    char* ws = (char*)d_ws;
    float* buf1  = (float*)ws;                         // Ds, then Ps (fp32)
    char*  buf2c = ws + MATB;                          // multi-use 64 MB
    float* buf2  = (float*)buf2c;                      // G (fp32)
    __hip_bfloat16* X2h = (__hip_bfloat16*)buf2c;                    // 1 MB
    __hip_bfloat16* X2l = (__hip_bfloat16*)(buf2c + (size_t)LDIM * CDIM * 2);
    __hip_bfloat16* A2b = (__hip_bfloat16*)buf2c;                    // 32 MB
    __hip_bfloat16* X1T = (__hip_bfloat16*)(buf2c + MATB / 2);       // 1 MB
    float* invn  = (float*)(ws + 2 * MATB);
    float* rowm  = invn + LDIM;
    float* rowrz = rowm + LDIM;

    const int B = in_sizes[0] / (LDIM * CDIM);

    hipMemsetAsync(d_out, 0, (size_t)out_size * sizeof(float), stream);

    for (int b = 0; b < B; ++b) {
        const float* X2b_ = x2 + (size_t)b * LDIM * CDIM;
        const float* X1b_ = x1 + (size_t)b * LDIM * CDIM;
        float* Yb = out + (size_t)b * LDIM * CDIM;

        k_split     <<<LDIM * CDIM / 1024, 256, 0, stream>>>(X2b_, X2h, X2l);
        k_gemm_d    <<<dim3(LDIM / 128, LDIM / 128), 256, 0, stream>>>(X2h, X2l, buf1);
        k_invnorm   <<<LDIM / 256, 256, 0, stream>>>(buf1, invn);
        k_gdiag     <<<dim3(LDIM / 1024, LDIM / 8), 256, 0, stream>>>(buf1, buf2);
        k_pool_stats<<<LDIM / 8, 256, 0, stream>>>(buf2, invn, buf1, rowm, rowrz);
        k_x1t       <<<LDIM / 32, 256, 0, stream>>>(X1b_, X1T);
        k_att2      <<<dim3(LDIM / 1024, LDIM / 8), 256, 0, stream>>>(buf1, rowm, rowrz, A2b);
        k_gemm_y    <<<dim3(LDIM / 128, 8), 256, 0, stream>>>(A2b, X1T, Yb);
    }
}